// Round 2
// baseline (165.998 us; speedup 1.0000x reference)
//
#include <hip/hip_runtime.h>
#include <hip/hip_bf16.h>

// relu(x[n,k,:] @ W + b) max-pooled over k.
// x: [100000, 32, 64] f32, W: [64, 64] f32 ([n_in][n_out]), b: [64] f32
// out: [100000, 64] f32
//
// One wave per node-iteration, bf16 MFMA 16x16x32, W in registers.
// 2-deep software pipeline: while MFMA+epilogue run on node n, the raw
// f32 tile for node n+S is converting and node n+2S's loads are in flight.
// 12500 waves x exactly 8 nodes each (no straggler tail).
// HBM floor: 845 MB -> ~134 us at 6.3 TB/s.

typedef __attribute__((ext_vector_type(8))) short bf16x8;
typedef __attribute__((ext_vector_type(4))) float f32x4;

#define KNEIGH 32
#define NIN 64
#define NOUT 64

__device__ __forceinline__ short f2bf(float f) {
    // standard RNE conversion -> compiler can pack pairs as v_cvt_pk_bf16_f32
    __hip_bfloat16 h = __float2bfloat16(f);
    return __builtin_bit_cast(short, h);
}

__device__ __forceinline__ void load_node(f32x4 xr[2][2][2], const float* __restrict__ xb,
                                          int l16, int lg) {
#pragma unroll
    for (int m = 0; m < 2; ++m) {
#pragma unroll
        for (int s = 0; s < 2; ++s) {
            const f32x4* p = reinterpret_cast<const f32x4*>(
                xb + (m * 16 + l16) * NIN + s * 32 + lg * 8);
            xr[m][s][0] = p[0];
            xr[m][s][1] = p[1];
        }
    }
}

__device__ __forceinline__ void convert_node(bf16x8 Af[2][2], const f32x4 xr[2][2][2]) {
#pragma unroll
    for (int m = 0; m < 2; ++m) {
#pragma unroll
        for (int s = 0; s < 2; ++s) {
#pragma unroll
            for (int j = 0; j < 4; ++j) {
                Af[m][s][j]     = f2bf(xr[m][s][0][j]);
                Af[m][s][4 + j] = f2bf(xr[m][s][1][j]);
            }
        }
    }
}

__global__ __launch_bounds__(256, 3) void edge_mfma_kernel(
    const float* __restrict__ x, const float* __restrict__ W,
    const float* __restrict__ b, float* __restrict__ out,
    int n_nodes, int wave_stride)
{
    const int lane = threadIdx.x & 63;
    const int l16  = lane & 15;
    const int lg   = lane >> 4;

    // ---- per-wave constants: W as 8 B-fragments, bias ----
    // B layout for 16x16x32: col n = lane&15, k = (lane>>4)*8 + j
    bf16x8 Wf[4][2];
#pragma unroll
    for (int t = 0; t < 4; ++t) {
#pragma unroll
        for (int s = 0; s < 2; ++s) {
#pragma unroll
            for (int j = 0; j < 8; ++j) {
                int k = s * 32 + lg * 8 + j;
                int o = t * 16 + l16;
                Wf[t][s][j] = f2bf(W[k * NOUT + o]);
            }
        }
    }
    float bias[4];
#pragma unroll
    for (int t = 0; t < 4; ++t) bias[t] = b[t * 16 + l16];

    const int S = wave_stride;
    int n = blockIdx.x * 4 + (threadIdx.x >> 6);
    if (n >= n_nodes) return;

    f32x4 xr[2][2][2];   // raw f32 tile in flight (node n+S)
    bf16x8 Af[2][2];     // converted fragments for current node n

    // ---- prologue ----
    load_node(xr, x + (size_t)n * (KNEIGH * NIN), l16, lg);
    convert_node(Af, xr);
    if (n + S < n_nodes)
        load_node(xr, x + (size_t)(n + S) * (KNEIGH * NIN), l16, lg);

    // ---- pipelined main loop ----
    for (; n < n_nodes; n += S) {
        // MFMA on node n (Af)
        f32x4 acc[2][4];
#pragma unroll
        for (int m = 0; m < 2; ++m)
#pragma unroll
            for (int t = 0; t < 4; ++t)
                acc[m][t] = (f32x4){0.f, 0.f, 0.f, 0.f};

#pragma unroll
        for (int m = 0; m < 2; ++m) {
#pragma unroll
            for (int t = 0; t < 4; ++t) {
                acc[m][t] = __builtin_amdgcn_mfma_f32_16x16x32_bf16(
                    Af[m][0], Wf[t][0], acc[m][t], 0, 0, 0);
                acc[m][t] = __builtin_amdgcn_mfma_f32_16x16x32_bf16(
                    Af[m][1], Wf[t][1], acc[m][t], 0, 0, 0);
            }
        }

        // rotate pipeline: convert node n+S, issue loads for node n+2S
        if (n + S < n_nodes) {
            convert_node(Af, xr);
            if (n + 2 * S < n_nodes)
                load_node(xr, x + (size_t)(n + 2 * S) * (KNEIGH * NIN), l16, lg);
        }

        // epilogue: max over 32 rows per column, relu(max + bias)
        // C/D layout: col = lane&15, row = (lane>>4)*4 + reg (+16 for m-tile 1)
        float res[4];
#pragma unroll
        for (int t = 0; t < 4; ++t) {
            float v0 = fmaxf(acc[0][t][0], acc[1][t][0]);
            float v1 = fmaxf(acc[0][t][1], acc[1][t][1]);
            float v2 = fmaxf(acc[0][t][2], acc[1][t][2]);
            float v3 = fmaxf(acc[0][t][3], acc[1][t][3]);
            float r = fmaxf(fmaxf(v0, v1), fmaxf(v2, v3));
            r = fmaxf(r, __shfl_xor(r, 16));
            r = fmaxf(r, __shfl_xor(r, 32));
            res[t] = fmaxf(r + bias[t], 0.0f);
        }

        float val = (lg == 0) ? res[0] : (lg == 1) ? res[1] : (lg == 2) ? res[2] : res[3];
        out[(size_t)n * NOUT + lane] = val;
    }
}

extern "C" void kernel_launch(void* const* d_in, const int* in_sizes, int n_in,
                              void* d_out, int out_size, void* d_ws, size_t ws_size,
                              hipStream_t stream) {
    const float* x = (const float*)d_in[0];
    const float* W = (const float*)d_in[1];
    const float* b = (const float*)d_in[2];
    float* out = (float*)d_out;

    const int n_nodes = in_sizes[0] / (KNEIGH * NIN);  // 100000
    // 12500 waves -> exactly 8 nodes per wave at N=100000 (no straggler tail)
    const int blocks = 3125;
    const int wave_stride = blocks * 4;

    hipLaunchKernelGGL(edge_mfma_kernel, dim3(blocks), dim3(256), 0, stream,
                       x, W, b, out, n_nodes, wave_stride);
}